// Round 14
// baseline (35.515 us; speedup 1.0000x reference)
//
#include <hip/hip_runtime.h>
#include <stdint.h>

#define N_PROP 2000
#define NCLS 80
#define MAXPC 100
#define MAXIMG 300
#define NFLAT (NCLS*MAXPC)   // 8000
#define CAP 768              // select_topt candidate cap (fallback)
#define SLOT 32              // per-class candidate slots (SLOT < MAXPC => rank proof)
#define KCAP 768             // global kept-list cap (mean ~625, sigma ~25)
#define TKEY 0xBF7F0000u     // fkey(0.99609375) candidate threshold
#define FKEY_NEGINF 0x007FFFFFu

#define ST_UNDEC 0
#define ST_KEPT 1
#define ST_SUPP 2

// persistent device scratch. g_kcnt/g_bad/g_done zero at load, re-zeroed at
// the END of every tail (both paths) -> every launch starts clean.
__device__ float4   g_boxes[N_PROP];        // fallback only
__device__ uint32_t g_adj[N_PROP * 64];     // fallback only (computed there)
__device__ unsigned char g_edge[N_PROP];    // fallback only
__device__ __align__(16) uint32_t g_outkey[NFLAT];   // fallback only
__device__ int      g_outidx[NFLAT];                 // fallback only
__device__ uint64_t g_kept[KCAP];           // global kept list (unordered)
__device__ int      g_kcnt;
__device__ int      g_bad;
__device__ int      g_done;                 // fan-in counter

__device__ __forceinline__ uint32_t fkey(float f) {
    uint32_t u = __float_as_uint(f);
    return (u & 0x80000000u) ? ~u : (u | 0x80000000u);
}
// packed order == global tie-break order: key desc, class asc, index asc
__device__ __forceinline__ uint64_t packe(uint32_t key, int c, int i) {
    return ((uint64_t)key << 18) | ((uint32_t)(127 - c) << 11) | (uint32_t)(2047 - i);
}
// 256 bins of width 2^8 over [TKEY, fkey(1.0)); entries always have key >= TKEY
__device__ __forceinline__ uint32_t tbin(uint64_t e) {
    uint32_t k = (uint32_t)(e >> 18);
    uint32_t b = (k - TKEY) >> 8;
    return b > 255u ? 255u : b;
}
// decode one proposal's box (bit-identical expression tree to all prior rounds)
__device__ __forceinline__ float4 decode_box(const float4 p, const float4 d) {
    float w = p.z - p.x + 1.0f, h = p.w - p.y + 1.0f;
    float cx = p.x + 0.5f*w,  cy = p.y + 0.5f*h;
    float pcx = d.x*w + cx, pcy = d.y*h + cy;
    float pw = expf(d.z)*w, ph = expf(d.w)*h;
    return make_float4(pcx - 0.5f*pw, pcy - 0.5f*ph, pcx + 0.5f*pw, pcy + 0.5f*ph);
}

// select_topt (round-8/10/12 proven, 1024 threads) — FALLBACK only.
__device__ void select_topt(const uint32_t* __restrict__ skey,
                            const unsigned char* state, int want,
                            int n, int t,
                            uint32_t* hist, uint32_t* binFill,
                            uint64_t* cand, uint64_t* outbuf, int* sh) {
    const int tid = threadIdx.x;
    const int lane = tid & 63;
    uint32_t prefix = 0, above = 0, thr = 0, Bi = 0, mask = 0x7FFu;
    int shift = 21, width = 11;
    bool tie = false;
    for (;;) {
        for (int b = tid; b <= 2048; b += 1024) hist[b] = 0;
        __syncthreads();
        for (int i0 = 0; i0 < n; i0 += 1024) {
            int i = i0 + tid;
            bool valid = false; uint32_t b = 0;
            if (i < n && (!state || state[i] == want)) {
                uint32_t k = skey[i];
                if (shift == 21 || (k >> (shift + width)) == prefix) {
                    valid = true; b = (k >> shift) & mask;
                }
            }
            uint32_t b0 = __shfl(b, 0);
            bool same = valid && (b == b0);
            unsigned long long eq = __ballot(same);
            if (eq == ~0ull) {
                if (lane == 0) atomicAdd(&hist[b0], 64u);
            } else if (valid) {
                atomicAdd(&hist[b], 1u);
            }
        }
        __syncthreads();
        if (tid < 256) {
            uint32_t c8 = 0;
            #pragma unroll 8
            for (int q = 0; q < 8; ++q) c8 += hist[tid*8 + q];
            binFill[tid] = c8;
        }
        __syncthreads();
        if (tid < 64) {
            uint32_t h0=binFill[4*lane], h1=binFill[4*lane+1], h2=binFill[4*lane+2], h3=binFill[4*lane+3];
            uint32_t T = h0+h1+h2+h3, I = T;
            for (int off = 1; off < 64; off <<= 1) {
                uint32_t v = __shfl_down(I, off);
                if (lane + off < 64) I += v;
            }
            uint32_t S = I - T;
            uint32_t o3=h3+S, o2=h2+o3, o1=h1+o2, o0=h0+o1;
            binFill[4*lane]=o0; binFill[4*lane+1]=o1; binFill[4*lane+2]=o2; binFill[4*lane+3]=o3;
        }
        __syncthreads();
        if (tid < 256) {
            uint32_t run = (tid == 255) ? 0u : binFill[tid+1];
            uint32_t t7,t6,t5,t4,t3,t2,t1,t0;
            run += hist[tid*8+7]; t7 = run;
            run += hist[tid*8+6]; t6 = run;
            run += hist[tid*8+5]; t5 = run;
            run += hist[tid*8+4]; t4 = run;
            run += hist[tid*8+3]; t3 = run;
            run += hist[tid*8+2]; t2 = run;
            run += hist[tid*8+1]; t1 = run;
            run += hist[tid*8+0]; t0 = run;
            hist[tid*8+0]=t0; hist[tid*8+1]=t1; hist[tid*8+2]=t2; hist[tid*8+3]=t3;
            hist[tid*8+4]=t4; hist[tid*8+5]=t5; hist[tid*8+6]=t6; hist[tid*8+7]=t7;
        }
        __syncthreads();
        if (tid < 256) {
            #pragma unroll 8
            for (int q = 0; q < 8; ++q) {
                int b = tid*8 + q;
                uint32_t sb = hist[b], sb1 = hist[b+1];
                if (above + sb >= (uint32_t)t && above + sb1 < (uint32_t)t) sh[1] = b;
            }
        }
        __syncthreads();
        int B = sh[1];
        uint32_t nCand = above + hist[B];
        uint32_t nAbove = above + hist[B+1];
        thr = (prefix << width) | (uint32_t)B;
        if (nCand <= CAP) { __syncthreads(); break; }
        if (shift == 0) {
            uint32_t needS = (uint32_t)t - nAbove;
            __syncthreads();
            for (int b = tid; b < 257; b += 1024) hist[b] = 0;
            __syncthreads();
            for (int i = tid; i < n; i += 1024)
                if ((!state || state[i] == want) && skey[i] == thr)
                    atomicAdd(&hist[i >> 5], 1u);
            __syncthreads();
            if (tid < 64) {
                uint32_t h0=hist[4*lane], h1=hist[4*lane+1], h2=hist[4*lane+2], h3=hist[4*lane+3];
                uint32_t T = h0+h1+h2+h3, I = T;
                for (int off = 1; off < 64; off <<= 1) {
                    uint32_t v = __shfl_up(I, off);
                    if (lane >= off) I += v;
                }
                uint32_t S = I - T;
                uint32_t a0=S+h0, a1=a0+h1, a2=a1+h2, a3=a2+h3;
                hist[4*lane]=a0; hist[4*lane+1]=a1; hist[4*lane+2]=a2; hist[4*lane+3]=a3;
            }
            __syncthreads();
            if (tid < 256) {
                if (hist[tid] >= needS && (tid == 0 || hist[tid-1] < needS)) sh[1] = tid;
            }
            __syncthreads();
            Bi = (uint32_t)sh[1];
            tie = true;
            __syncthreads();
            break;
        }
        prefix = thr; above = nAbove;
        if (shift == 21) { shift = 10; width = 11; mask = 0x7FFu; }
        else             { shift = 0;  width = 10; mask = 0x3FFu; }
        __syncthreads();
    }

    if (!tie && above == 0) {
        for (int b = tid; b < 2048; b += 1024) binFill[b] = 0;
        __syncthreads();
        for (int i = tid; i < n; i += 1024) {
            if (!state || state[i] == want) {
                uint32_t k = skey[i];
                if ((k >> shift) >= thr) {
                    uint32_t be = (k >> shift) & mask;
                    uint32_t pos = hist[be+1] + atomicAdd(&binFill[be], 1u);
                    cand[pos] = ((uint64_t)k << 32) | (uint32_t)(0xFFFFFFFFu - (uint32_t)i);
                }
            }
        }
        __syncthreads();
        int m = (int)hist[thr & mask];
        for (int s = tid; s < m; s += 1024) {
            uint64_t e = cand[s];
            uint32_t k = (uint32_t)(e >> 32);
            uint32_t be = (k >> shift) & mask;
            uint32_t base = hist[be+1];
            uint32_t cnt = hist[be] - base;
            uint32_t r = base;
            for (uint32_t s2 = base; s2 < base + cnt; ++s2)
                r += (cand[s2] > e) ? 1u : 0u;
            if (r < (uint32_t)t) outbuf[r] = e;
        }
        __syncthreads();
    } else {
        if (tid == 0) sh[2] = 0;
        __syncthreads();
        for (int i0 = 0; i0 < n; i0 += 1024) {
            int i = i0 + tid;
            bool take = false; uint32_t k = 0;
            if (i < n && (!state || state[i] == want)) {
                k = skey[i];
                take = tie ? (k > thr || (k == thr && (uint32_t)(i >> 5) <= Bi))
                           : ((k >> shift) >= thr);
            }
            unsigned long long mm = __ballot(take);
            if (mm) {
                int leader = __ffsll((long long)mm) - 1;
                int wbase = 0;
                if (lane == leader) wbase = atomicAdd(&sh[2], (int)__popcll(mm));
                wbase = __shfl(wbase, leader);
                if (take) {
                    int pos = wbase + __popcll(mm & ((1ull << lane) - 1ull));
                    cand[pos] = ((uint64_t)k << 32) | (uint32_t)(0xFFFFFFFFu - (uint32_t)i);
                }
            }
        }
        __syncthreads();
        int m = sh[2];
        for (int s = tid; s < m; s += 1024) {
            uint64_t e = cand[s];
            uint32_t r = 0;
            for (int s2 = 0; s2 < m; ++s2) r += (cand[s2] > e) ? 1u : 0u;
            if (r < (uint32_t)t) outbuf[r] = e;
        }
        __syncthreads();
    }
}

// LDS layout (57 KB; fast path uses a fraction)
#define SM_A      0        // fast: keptb 0-6144 | fallback: skey 0-8000, state 8000-10016, gkey 0-32000
#define SM_HIST   32000    // 2052*4 (fast uses [0..256])
#define SM_BINF   40208    // 2048*4 (fast uses [0..255])
#define SM_OUT    48400    // 304*8
#define SM_SH     50832    // 64
#define SM_CAND   50896    // 768*8 (fast compaction + fallback select)
#define SM_BYTES  57040

// 80 blocks x 1024: class c = blockIdx.x — extract candidates (score >= TKEY),
// decode boxes, in-register pairwise IoU, greedy (== full greedy, proven
// R11-R13), append kept; last-finishing block (R8-proven fan-in) ranks the
// ~625 kept entries -> top-300 -> output. Fallback: from-scratch recompute.
__global__ __launch_bounds__(1024) void fused_kernel(const float* __restrict__ deltas,
                                                     const float* __restrict__ props,
                                                     const float* __restrict__ scores,
                                                     float* __restrict__ out) {
    __shared__ __align__(16) char smem[SM_BYTES];
    __shared__ uint64_t sl[SLOT];
    __shared__ int s_cnt;
    __shared__ int s_ch[3];
    uint64_t* keptb = (uint64_t*)(smem + SM_A);
    uint32_t* hist  = (uint32_t*)(smem + SM_HIST);
    uint32_t* binF  = (uint32_t*)(smem + SM_BINF);
    uint64_t* outbuf= (uint64_t*)(smem + SM_OUT);
    int* sh         = (int*)(smem + SM_SH);
    uint64_t* cand2 = (uint64_t*)(smem + SM_CAND);
    const int c = blockIdx.x, tid = threadIdx.x;
    const int lane = tid & 63;

    // ---- class phase ----
    if (tid == 0) s_cnt = 0;
    __syncthreads();
    for (int i = tid; i < N_PROP; i += 1024) {
        uint32_t k = fkey(scores[i * NCLS + c]);
        if (k >= TKEY) {
            int pos = atomicAdd(&s_cnt, 1);
            if (pos < SLOT) sl[pos] = packe(k, c, i);
        }
    }
    __syncthreads();
    const int v = s_cnt;
    if (v > SLOT && tid == 0) g_bad = 1;
    if (v >= 1 && v <= SLOT && tid < 64) {
        // in-place rank sort desc (u64-unique keys; same-wave lockstep — R11-R13)
        uint64_t e = (lane < v) ? sl[lane] : 0ull;
        int r = 0;
        if (lane < v) {
            for (int j = 0; j < v; ++j) r += (sl[j] > e) ? 1 : 0;
            sl[r] = e;
        }
        uint64_t se = (lane < v) ? sl[lane] : 0ull;
        const int i_me = 2047 - (int)(se & 0x7FF);
        float4 bx = make_float4(0.f, 0.f, 0.f, 0.f);
        if (lane < v)
            bx = decode_box(((const float4*)props)[i_me], ((const float4*)deltas)[i_me]);
        const float ar = fmaxf(bx.z - bx.x, 0.0f) * fmaxf(bx.w - bx.y, 0.0f);
        uint32_t row = 0;
        #pragma unroll
        for (int b = 0; b < SLOT; ++b) {
            float x1 = __shfl(bx.x, b), y1 = __shfl(bx.y, b);
            float x2 = __shfl(bx.z, b), y2 = __shfl(bx.w, b);
            float ab = __shfl(ar, b);
            if (lane < v && b < v && b != lane) {
                float ix1 = fmaxf(bx.x, x1);
                float iy1 = fmaxf(bx.y, y1);
                float ix2 = fminf(bx.z, x2);
                float iy2 = fminf(bx.w, y2);
                float inter = fmaxf(ix2 - ix1, 0.0f) * fmaxf(iy2 - iy1, 0.0f);
                float uni = ar + ab - inter;
                if (inter > 0.7f * uni) row |= 1u << b;
            }
        }
        uint32_t supp = 0, kept = 0;
        for (int rr = 0; rr < v; ++rr) {
            uint32_t rowr = (uint32_t)__shfl((int)row, rr);
            if (!((supp >> rr) & 1u)) { kept |= 1u << rr; supp |= rowr; }
        }
        bool take = (lane < v) && ((kept >> lane) & 1u);
        unsigned long long mm = __ballot(take);
        if (mm) {
            int leader = __ffsll((long long)mm) - 1;
            int wbase = 0;
            if (lane == leader) wbase = atomicAdd(&g_kcnt, (int)__popcll(mm));
            wbase = __shfl(wbase, leader);
            if (take) {
                int pos = wbase + __popcll(mm & ((1ull << lane) - 1ull));
                if (pos < KCAP) g_kept[pos] = se;
            }
        }
    }

    // ---- fan-in: last block to finish runs the tail (R8-proven pattern) ----
    __syncthreads();
    __threadfence();                                // release kept/g_bad writes
    if (tid == 0) sh[3] = atomicAdd(&g_done, 1);
    __syncthreads();
    if (sh[3] != NCLS - 1) return;
    __threadfence();                                // acquire others' writes

    if (tid == 0) { sh[6] = g_kcnt; sh[7] = g_bad; }
    __syncthreads();
    const int total = sh[6];
    bool fast = (!sh[7]) && (total >= MAXIMG) && (total <= KCAP);

    if (fast) {
        for (int s = tid; s < total; s += 1024) keptb[s] = g_kept[s];
        if (tid < 257) hist[tid] = 0;
        __syncthreads();
        for (int s = tid; s < total; s += 1024)
            atomicAdd(&hist[tbin(keptb[s])], 1u);
        __syncthreads();
        // suffix scan hist[0..255] by one wave; hist[256] stays 0
        if (tid < 64) {
            uint32_t h0=hist[4*lane], h1=hist[4*lane+1], h2=hist[4*lane+2], h3=hist[4*lane+3];
            uint32_t T = h0+h1+h2+h3, I = T;
            for (int off = 1; off < 64; off <<= 1) {
                uint32_t vv = __shfl_down(I, off);
                if (lane + off < 64) I += vv;
            }
            uint32_t S = I - T;
            uint32_t o3=h3+S, o2=h2+o3, o1=h1+o2, o0=h0+o1;
            hist[4*lane]=o0; hist[4*lane+1]=o1; hist[4*lane+2]=o2; hist[4*lane+3]=o3;
        }
        __syncthreads();
        if (tid < 256) {
            if (hist[tid] >= (uint32_t)MAXIMG && hist[tid+1] < (uint32_t)MAXIMG) sh[1] = tid;
        }
        __syncthreads();
        const uint32_t B = (uint32_t)sh[1];
        const int nCand = (int)hist[B];      // <= total <= KCAP == cand2 capacity
        if (tid < 256) binF[tid] = 0;
        __syncthreads();
        for (int s = tid; s < total; s += 1024) {
            uint64_t e = keptb[s];
            uint32_t b = tbin(e);
            if (b >= B) {
                uint32_t pos = hist[b+1] + atomicAdd(&binF[b], 1u);
                cand2[pos] = e;
            }
        }
        __syncthreads();
        for (int s = tid; s < nCand; s += 1024) {
            uint64_t e = cand2[s];
            uint32_t b = tbin(e);
            uint32_t base = hist[b+1];
            uint32_t cnt2 = hist[b] - base;
            uint32_t r = base;
            for (uint32_t s2 = base; s2 < base + cnt2; ++s2)
                r += (cand2[s2] > e) ? 1u : 0u;
            if (r < (uint32_t)MAXIMG) outbuf[r] = e;
        }
        __syncthreads();
        // winners' in-class kept-rank < v <= 32 < 100 by construction
        if (tid < MAXIMG) {
            uint64_t e = outbuf[tid];
            int i = 2047 - (int)(e & 0x7FF);
            int wc = 127 - (int)((e >> 11) & 0x7F);
            float4 b = decode_box(((const float4*)props)[i], ((const float4*)deltas)[i]);
            out[tid*4+0] = b.x;
            out[tid*4+1] = b.y;
            out[tid*4+2] = b.z;
            out[tid*4+3] = b.w;
            out[MAXIMG*4 + tid] = (float)wc;
        }
        if (tid == 0) { g_kcnt = 0; g_bad = 0; g_done = 0; }
        return;
    }

    // ============ FALLBACK (correctness net; never runs on bench data) ============
    {
        for (int i = tid; i < N_PROP; i += 1024)
            g_boxes[i] = decode_box(((const float4*)props)[i], ((const float4*)deltas)[i]);
        __syncthreads();
        for (int w = tid; w < N_PROP * 64; w += 1024) {
            int rowi = w >> 6, wd = w & 63;
            float4 bi = g_boxes[rowi];
            float ai = fmaxf(bi.z - bi.x, 0.0f) * fmaxf(bi.w - bi.y, 0.0f);
            uint32_t bits = 0u;
            for (int b = 0; b < 32; ++b) {
                int j = wd * 32 + b;
                if (j < N_PROP && j != rowi) {
                    float4 bj = g_boxes[j];
                    float aj = fmaxf(bj.z - bj.x, 0.0f) * fmaxf(bj.w - bj.y, 0.0f);
                    float ix1 = fmaxf(bi.x, bj.x);
                    float iy1 = fmaxf(bi.y, bj.y);
                    float ix2 = fminf(bi.z, bj.z);
                    float iy2 = fminf(bi.w, bj.w);
                    float inter = fmaxf(ix2 - ix1, 0.0f) * fmaxf(iy2 - iy1, 0.0f);
                    float uni = ai + aj - inter;
                    if (inter > 0.7f * uni) bits |= (1u << b);
                }
            }
            g_adj[w] = bits;
        }
        __syncthreads();
        for (int i = tid; i < N_PROP; i += 1024) {
            uint32_t any = 0u;
            for (int w2 = 0; w2 < 64; ++w2) any |= g_adj[i * 64 + w2];
            g_edge[i] = any ? 1 : 0;
        }
        __syncthreads();

        uint32_t* skey = (uint32_t*)(smem + SM_A);
        unsigned char* state = (unsigned char*)(smem + SM_A + 8000);
        uint64_t* cand = cand2;
        for (int c2 = 0; c2 < NCLS; ++c2) {
            for (int i = tid; i < N_PROP; i += 1024) {
                skey[i] = fkey(scores[i * NCLS + c2]);
                state[i] = g_edge[i] ? ST_UNDEC : ST_KEPT;
            }
            if (tid < 3) s_ch[tid] = 0;
            __syncthreads();
            int p = 0;
            for (;;) {
                s_ch[(p+1) % 3] = 0;
                for (int i = tid; i < N_PROP; i += 1024) {
                    if (state[i] != ST_UNDEC) continue;
                    uint32_t ki = skey[i];
                    bool anyKept = false, anyUndec = false;
                    for (int w2 = 0; w2 < 64; ++w2) {
                        uint32_t bits = g_adj[i * 64 + w2];
                        while (bits) {
                            int b = __ffs(bits) - 1; bits &= bits - 1;
                            int j = w2 * 32 + b;
                            uint32_t kj = skey[j];
                            if (kj > ki || (kj == ki && j < i)) {
                                unsigned char stj = state[j];
                                if (stj == ST_KEPT) anyKept = true;
                                else if (stj == ST_UNDEC) anyUndec = true;
                            }
                        }
                    }
                    if (anyKept)        { state[i] = ST_SUPP; s_ch[p] = 1; }
                    else if (!anyUndec) { state[i] = ST_KEPT; s_ch[p] = 1; }
                }
                __syncthreads();
                if (!s_ch[p]) break;
                p = (p + 1) % 3;
            }
            if (tid == 0) sh[5] = 0;
            __syncthreads();
            {
                int local = 0;
                for (int i = tid; i < N_PROP; i += 1024) local += (state[i] == ST_KEPT) ? 1 : 0;
                if (local) atomicAdd(&sh[5], local);
            }
            __syncthreads();
            const int kept = sh[5];
            const int t1 = kept < MAXPC ? kept : MAXPC;
            select_topt(skey, state, ST_KEPT, N_PROP, t1, hist, binF, cand, outbuf, sh);
            for (int r = tid; r < t1; r += 1024) {
                uint64_t e = outbuf[r];
                g_outkey[c2 * MAXPC + r] = (uint32_t)(e >> 32);
                g_outidx[c2 * MAXPC + r] = (int)(0xFFFFFFFFu - (uint32_t)e);
            }
            if (kept < MAXPC) {
                __syncthreads();
                const int t2 = MAXPC - kept;
                select_topt(skey, state, ST_SUPP, N_PROP, t2, hist, binF, cand, outbuf, sh);
                for (int r = tid; r < t2; r += 1024) {
                    uint64_t e = outbuf[r];
                    g_outkey[c2 * MAXPC + kept + r] = FKEY_NEGINF;
                    g_outidx[c2 * MAXPC + kept + r] = (int)(0xFFFFFFFFu - (uint32_t)e);
                }
            }
            __syncthreads();
        }
        uint32_t* gkey = (uint32_t*)(smem + SM_A);
        const uint4* gk4 = (const uint4*)g_outkey;
        uint4* lk4 = (uint4*)gkey;
        for (int q = tid; q < NFLAT/4; q += 1024) lk4[q] = gk4[q];
        __syncthreads();
        select_topt(gkey, nullptr, 0, NFLAT, MAXIMG, hist, binF, cand, outbuf, sh);
        for (int r = tid; r < MAXIMG; r += 1024) {
            uint64_t e = outbuf[r];
            int f = (int)(0xFFFFFFFFu - (uint32_t)e);
            int pi = g_outidx[f];
            float4 b = g_boxes[pi];
            out[r*4+0] = b.x;
            out[r*4+1] = b.y;
            out[r*4+2] = b.z;
            out[r*4+3] = b.w;
            out[MAXIMG*4 + r] = (float)(f / MAXPC);
        }
        if (tid == 0) { g_kcnt = 0; g_bad = 0; g_done = 0; }
    }
}

extern "C" void kernel_launch(void* const* d_in, const int* in_sizes, int n_in,
                              void* d_out, int out_size, void* d_ws, size_t ws_size,
                              hipStream_t stream) {
    const float* deltas = (const float*)d_in[0];   // roi_bboxes_txtytwth [2000,4]
    const float* scores = (const float*)d_in[1];   // roi_score [2000,80]
    const float* props  = (const float*)d_in[2];   // rpn_proposals_bboxes [2000,4]
    float* out = (float*)d_out;                    // 1200 box floats + 300 class floats

    fused_kernel<<<NCLS, 1024, 0, stream>>>(deltas, props, scores, out);
}

// Round 15
// 15.394 us; speedup vs baseline: 2.3070x; 2.3070x over previous
//
#include <hip/hip_runtime.h>
#include <stdint.h>

#define N_PROP 2000
#define NCLS 80
#define MAXPC 100
#define MAXIMG 300
#define NFLAT (NCLS*MAXPC)   // 8000
#define CAP 768              // select_topt candidate cap (fallback)
#define SLOT 32              // per-class candidate slots (SLOT < MAXPC => rank proof)
#define KCAP 768             // global kept-list cap (mean ~625, sigma ~25)
#define TKEY 0xBF7F0000u     // fkey(0.99609375) candidate threshold
#define FKEY_NEGINF 0x007FFFFFu

#define ST_UNDEC 0
#define ST_KEPT 1
#define ST_SUPP 2

// persistent device scratch. g_kcnt/g_bad zero at load, re-zeroed at END of
// every tail run (both paths) -> every launch starts clean.
__device__ float4   g_boxes[N_PROP];        // fallback only
__device__ uint32_t g_adj[N_PROP * 64];     // fallback only (computed there)
__device__ unsigned char g_edge[N_PROP];    // fallback only
__device__ __align__(16) uint32_t g_outkey[NFLAT];   // fallback only
__device__ int      g_outidx[NFLAT];                 // fallback only
__device__ uint64_t g_kept[KCAP];           // global kept list (unordered)
__device__ int      g_kcnt;
__device__ int      g_bad;

__device__ __forceinline__ uint32_t fkey(float f) {
    uint32_t u = __float_as_uint(f);
    return (u & 0x80000000u) ? ~u : (u | 0x80000000u);
}
// packed order == global tie-break order: key desc, class asc, index asc
__device__ __forceinline__ uint64_t packe(uint32_t key, int c, int i) {
    return ((uint64_t)key << 18) | ((uint32_t)(127 - c) << 11) | (uint32_t)(2047 - i);
}
// 256 bins of width 2^8 over [TKEY, fkey(1.0)); entries always have key >= TKEY
__device__ __forceinline__ uint32_t tbin(uint64_t e) {
    uint32_t k = (uint32_t)(e >> 18);
    uint32_t b = (k - TKEY) >> 8;
    return b > 255u ? 255u : b;
}
// decode one proposal's box (bit-identical expression tree to all prior rounds)
__device__ __forceinline__ float4 decode_box(const float4 p, const float4 d) {
    float w = p.z - p.x + 1.0f, h = p.w - p.y + 1.0f;
    float cx = p.x + 0.5f*w,  cy = p.y + 0.5f*h;
    float pcx = d.x*w + cx, pcy = d.y*h + cy;
    float pw = expf(d.z)*w, ph = expf(d.w)*h;
    return make_float4(pcx - 0.5f*pw, pcy - 0.5f*ph, pcx + 0.5f*pw, pcy + 0.5f*ph);
}

// 80 blocks x 1024: extract class-c candidates (score >= TKEY), decode their
// boxes, in-register pairwise IoU, greedy NMS (== full greedy on >=TKEY verts,
// proven R11-R13), append kept to global list.
__global__ __launch_bounds__(1024) void class_kernel(const float* __restrict__ deltas,
                                                     const float* __restrict__ props,
                                                     const float* __restrict__ scores) {
    __shared__ uint64_t sl[SLOT];
    __shared__ int s_cnt;
    const int c = blockIdx.x, tid = threadIdx.x;
    if (tid == 0) s_cnt = 0;
    __syncthreads();
    for (int i = tid; i < N_PROP; i += 1024) {
        uint32_t k = fkey(scores[i * NCLS + c]);
        if (k >= TKEY) {
            int pos = atomicAdd(&s_cnt, 1);
            if (pos < SLOT) sl[pos] = packe(k, c, i);
        }
    }
    __syncthreads();
    const int v = s_cnt;
    if (v > SLOT) { if (tid == 0) g_bad = 1; return; }
    if (v == 0) return;
    if (tid >= 64) return;              // wave 0 finishes the class
    const int lane = tid;
    // in-place rank sort desc (u64-unique keys; same-wave lockstep — R11-R13 proven)
    uint64_t e = (lane < v) ? sl[lane] : 0ull;
    int r = 0;
    if (lane < v) {
        for (int j = 0; j < v; ++j) r += (sl[j] > e) ? 1 : 0;
        sl[r] = e;
    }
    uint64_t se = (lane < v) ? sl[lane] : 0ull;
    const int i_me = 2047 - (int)(se & 0x7FF);
    // decode my candidate's box (gather)
    float4 bx = make_float4(0.f, 0.f, 0.f, 0.f);
    if (lane < v)
        bx = decode_box(((const float4*)props)[i_me], ((const float4*)deltas)[i_me]);
    const float ar = fmaxf(bx.z - bx.x, 0.0f) * fmaxf(bx.w - bx.y, 0.0f);
    // pairwise IoU via shuffles: row bit b == (IoU(me, cand b) > 0.7)
    uint32_t row = 0;
    #pragma unroll
    for (int b = 0; b < SLOT; ++b) {
        float x1 = __shfl(bx.x, b), y1 = __shfl(bx.y, b);
        float x2 = __shfl(bx.z, b), y2 = __shfl(bx.w, b);
        float ab = __shfl(ar, b);
        if (lane < v && b < v && b != lane) {
            float ix1 = fmaxf(bx.x, x1);
            float iy1 = fmaxf(bx.y, y1);
            float ix2 = fminf(bx.z, x2);
            float iy2 = fminf(bx.w, y2);
            float inter = fmaxf(ix2 - ix1, 0.0f) * fmaxf(iy2 - iy1, 0.0f);
            float uni = ar + ab - inter;
            if (inter > 0.7f * uni) row |= 1u << b;
        }
    }
    // greedy over sorted order (all lanes redundantly)
    uint32_t supp = 0, kept = 0;
    for (int rr = 0; rr < v; ++rr) {
        uint32_t rowr = (uint32_t)__shfl((int)row, rr);
        if (!((supp >> rr) & 1u)) { kept |= 1u << rr; supp |= rowr; }
    }
    // append kept entries (one atomic per class)
    bool take = (lane < v) && ((kept >> lane) & 1u);
    unsigned long long mm = __ballot(take);
    if (mm) {
        int leader = __ffsll((long long)mm) - 1;
        int wbase = 0;
        if (lane == leader) wbase = atomicAdd(&g_kcnt, (int)__popcll(mm));
        wbase = __shfl(wbase, leader);
        if (take) {
            int pos = wbase + __popcll(mm & ((1ull << lane) - 1ull));
            if (pos < KCAP) g_kept[pos] = se;
        }
    }
}

// select_topt (round-8/10/12 proven, 1024 threads) — FALLBACK only.
__device__ void select_topt(const uint32_t* __restrict__ skey,
                            const unsigned char* state, int want,
                            int n, int t,
                            uint32_t* hist, uint32_t* binFill,
                            uint64_t* cand, uint64_t* outbuf, int* sh) {
    const int tid = threadIdx.x;
    const int lane = tid & 63;
    uint32_t prefix = 0, above = 0, thr = 0, Bi = 0, mask = 0x7FFu;
    int shift = 21, width = 11;
    bool tie = false;
    for (;;) {
        for (int b = tid; b <= 2048; b += 1024) hist[b] = 0;
        __syncthreads();
        for (int i0 = 0; i0 < n; i0 += 1024) {
            int i = i0 + tid;
            bool valid = false; uint32_t b = 0;
            if (i < n && (!state || state[i] == want)) {
                uint32_t k = skey[i];
                if (shift == 21 || (k >> (shift + width)) == prefix) {
                    valid = true; b = (k >> shift) & mask;
                }
            }
            uint32_t b0 = __shfl(b, 0);
            bool same = valid && (b == b0);
            unsigned long long eq = __ballot(same);
            if (eq == ~0ull) {
                if (lane == 0) atomicAdd(&hist[b0], 64u);
            } else if (valid) {
                atomicAdd(&hist[b], 1u);
            }
        }
        __syncthreads();
        if (tid < 256) {
            uint32_t c8 = 0;
            #pragma unroll 8
            for (int q = 0; q < 8; ++q) c8 += hist[tid*8 + q];
            binFill[tid] = c8;
        }
        __syncthreads();
        if (tid < 64) {
            uint32_t h0=binFill[4*lane], h1=binFill[4*lane+1], h2=binFill[4*lane+2], h3=binFill[4*lane+3];
            uint32_t T = h0+h1+h2+h3, I = T;
            for (int off = 1; off < 64; off <<= 1) {
                uint32_t v = __shfl_down(I, off);
                if (lane + off < 64) I += v;
            }
            uint32_t S = I - T;
            uint32_t o3=h3+S, o2=h2+o3, o1=h1+o2, o0=h0+o1;
            binFill[4*lane]=o0; binFill[4*lane+1]=o1; binFill[4*lane+2]=o2; binFill[4*lane+3]=o3;
        }
        __syncthreads();
        if (tid < 256) {
            uint32_t run = (tid == 255) ? 0u : binFill[tid+1];
            uint32_t t7,t6,t5,t4,t3,t2,t1,t0;
            run += hist[tid*8+7]; t7 = run;
            run += hist[tid*8+6]; t6 = run;
            run += hist[tid*8+5]; t5 = run;
            run += hist[tid*8+4]; t4 = run;
            run += hist[tid*8+3]; t3 = run;
            run += hist[tid*8+2]; t2 = run;
            run += hist[tid*8+1]; t1 = run;
            run += hist[tid*8+0]; t0 = run;
            hist[tid*8+0]=t0; hist[tid*8+1]=t1; hist[tid*8+2]=t2; hist[tid*8+3]=t3;
            hist[tid*8+4]=t4; hist[tid*8+5]=t5; hist[tid*8+6]=t6; hist[tid*8+7]=t7;
        }
        __syncthreads();
        if (tid < 256) {
            #pragma unroll 8
            for (int q = 0; q < 8; ++q) {
                int b = tid*8 + q;
                uint32_t sb = hist[b], sb1 = hist[b+1];
                if (above + sb >= (uint32_t)t && above + sb1 < (uint32_t)t) sh[1] = b;
            }
        }
        __syncthreads();
        int B = sh[1];
        uint32_t nCand = above + hist[B];
        uint32_t nAbove = above + hist[B+1];
        thr = (prefix << width) | (uint32_t)B;
        if (nCand <= CAP) { __syncthreads(); break; }
        if (shift == 0) {
            uint32_t needS = (uint32_t)t - nAbove;
            __syncthreads();
            for (int b = tid; b < 257; b += 1024) hist[b] = 0;
            __syncthreads();
            for (int i = tid; i < n; i += 1024)
                if ((!state || state[i] == want) && skey[i] == thr)
                    atomicAdd(&hist[i >> 5], 1u);
            __syncthreads();
            if (tid < 64) {
                uint32_t h0=hist[4*lane], h1=hist[4*lane+1], h2=hist[4*lane+2], h3=hist[4*lane+3];
                uint32_t T = h0+h1+h2+h3, I = T;
                for (int off = 1; off < 64; off <<= 1) {
                    uint32_t v = __shfl_up(I, off);
                    if (lane >= off) I += v;
                }
                uint32_t S = I - T;
                uint32_t a0=S+h0, a1=a0+h1, a2=a1+h2, a3=a2+h3;
                hist[4*lane]=a0; hist[4*lane+1]=a1; hist[4*lane+2]=a2; hist[4*lane+3]=a3;
            }
            __syncthreads();
            if (tid < 256) {
                if (hist[tid] >= needS && (tid == 0 || hist[tid-1] < needS)) sh[1] = tid;
            }
            __syncthreads();
            Bi = (uint32_t)sh[1];
            tie = true;
            __syncthreads();
            break;
        }
        prefix = thr; above = nAbove;
        if (shift == 21) { shift = 10; width = 11; mask = 0x7FFu; }
        else             { shift = 0;  width = 10; mask = 0x3FFu; }
        __syncthreads();
    }

    if (!tie && above == 0) {
        for (int b = tid; b < 2048; b += 1024) binFill[b] = 0;
        __syncthreads();
        for (int i = tid; i < n; i += 1024) {
            if (!state || state[i] == want) {
                uint32_t k = skey[i];
                if ((k >> shift) >= thr) {
                    uint32_t be = (k >> shift) & mask;
                    uint32_t pos = hist[be+1] + atomicAdd(&binFill[be], 1u);
                    cand[pos] = ((uint64_t)k << 32) | (uint32_t)(0xFFFFFFFFu - (uint32_t)i);
                }
            }
        }
        __syncthreads();
        int m = (int)hist[thr & mask];
        for (int s = tid; s < m; s += 1024) {
            uint64_t e = cand[s];
            uint32_t k = (uint32_t)(e >> 32);
            uint32_t be = (k >> shift) & mask;
            uint32_t base = hist[be+1];
            uint32_t cnt = hist[be] - base;
            uint32_t r = base;
            for (uint32_t s2 = base; s2 < base + cnt; ++s2)
                r += (cand[s2] > e) ? 1u : 0u;
            if (r < (uint32_t)t) outbuf[r] = e;
        }
        __syncthreads();
    } else {
        if (tid == 0) sh[2] = 0;
        __syncthreads();
        for (int i0 = 0; i0 < n; i0 += 1024) {
            int i = i0 + tid;
            bool take = false; uint32_t k = 0;
            if (i < n && (!state || state[i] == want)) {
                k = skey[i];
                take = tie ? (k > thr || (k == thr && (uint32_t)(i >> 5) <= Bi))
                           : ((k >> shift) >= thr);
            }
            unsigned long long mm = __ballot(take);
            if (mm) {
                int leader = __ffsll((long long)mm) - 1;
                int wbase = 0;
                if (lane == leader) wbase = atomicAdd(&sh[2], (int)__popcll(mm));
                wbase = __shfl(wbase, leader);
                if (take) {
                    int pos = wbase + __popcll(mm & ((1ull << lane) - 1ull));
                    cand[pos] = ((uint64_t)k << 32) | (uint32_t)(0xFFFFFFFFu - (uint32_t)i);
                }
            }
        }
        __syncthreads();
        int m = sh[2];
        for (int s = tid; s < m; s += 1024) {
            uint64_t e = cand[s];
            uint32_t r = 0;
            for (int s2 = 0; s2 < m; ++s2) r += (cand[s2] > e) ? 1u : 0u;
            if (r < (uint32_t)t) outbuf[r] = e;
        }
        __syncthreads();
    }
}

// LDS layout (57 KB; fast path uses a fraction)
#define SM_A      0        // fast: keptb 0-6144 | fallback: skey 0-8000, state 8000-10016, gkey 0-32000
#define SM_HIST   32000    // 2052*4 (fast uses [0..256])
#define SM_BINF   40208    // 2048*4 (fast uses [0..255])
#define SM_OUT    48400    // 304*8
#define SM_SH     50832    // 64
#define SM_CAND   50896    // 768*8 (fast compaction + fallback select)
#define SM_BYTES  57040

// single block x 1024: rank ~625 kept entries (256-bin histogram) -> top-300,
// decode winner boxes directly. Fallback recomputes everything from scratch.
__global__ __launch_bounds__(1024) void tail_kernel(const float* __restrict__ deltas,
                                                    const float* __restrict__ props,
                                                    const float* __restrict__ scores,
                                                    float* __restrict__ out) {
    __shared__ __align__(16) char smem[SM_BYTES];
    __shared__ int s_ch[3];
    uint64_t* keptb = (uint64_t*)(smem + SM_A);
    uint32_t* hist  = (uint32_t*)(smem + SM_HIST);
    uint32_t* binF  = (uint32_t*)(smem + SM_BINF);
    uint64_t* outbuf= (uint64_t*)(smem + SM_OUT);
    int* sh         = (int*)(smem + SM_SH);
    uint64_t* cand2 = (uint64_t*)(smem + SM_CAND);
    const int tid = threadIdx.x;
    const int lane = tid & 63;

    if (tid == 0) { sh[6] = g_kcnt; sh[7] = g_bad; }
    __syncthreads();
    const int total = sh[6];
    bool fast = (!sh[7]) && (total >= MAXIMG) && (total <= KCAP);

    if (fast) {
        for (int s = tid; s < total; s += 1024) keptb[s] = g_kept[s];
        if (tid < 257) hist[tid] = 0;
        __syncthreads();
        for (int s = tid; s < total; s += 1024)
            atomicAdd(&hist[tbin(keptb[s])], 1u);
        __syncthreads();
        // suffix scan hist[0..255] by one wave; hist[256] stays 0
        if (tid < 64) {
            uint32_t h0=hist[4*lane], h1=hist[4*lane+1], h2=hist[4*lane+2], h3=hist[4*lane+3];
            uint32_t T = h0+h1+h2+h3, I = T;
            for (int off = 1; off < 64; off <<= 1) {
                uint32_t v = __shfl_down(I, off);
                if (lane + off < 64) I += v;
            }
            uint32_t S = I - T;
            uint32_t o3=h3+S, o2=h2+o3, o1=h1+o2, o0=h0+o1;
            hist[4*lane]=o0; hist[4*lane+1]=o1; hist[4*lane+2]=o2; hist[4*lane+3]=o3;
        }
        __syncthreads();
        if (tid < 256) {
            if (hist[tid] >= (uint32_t)MAXIMG && hist[tid+1] < (uint32_t)MAXIMG) sh[1] = tid;
        }
        __syncthreads();
        const uint32_t B = (uint32_t)sh[1];
        const int nCand = (int)hist[B];      // <= total <= KCAP == cand2 capacity
        if (tid < 256) binF[tid] = 0;
        __syncthreads();
        for (int s = tid; s < total; s += 1024) {
            uint64_t e = keptb[s];
            uint32_t b = tbin(e);
            if (b >= B) {
                uint32_t pos = hist[b+1] + atomicAdd(&binF[b], 1u);
                cand2[pos] = e;
            }
        }
        __syncthreads();
        for (int s = tid; s < nCand; s += 1024) {
            uint64_t e = cand2[s];
            uint32_t b = tbin(e);
            uint32_t base = hist[b+1];
            uint32_t cnt2 = hist[b] - base;
            uint32_t r = base;
            for (uint32_t s2 = base; s2 < base + cnt2; ++s2)
                r += (cand2[s2] > e) ? 1u : 0u;
            if (r < (uint32_t)MAXIMG) outbuf[r] = e;
        }
        __syncthreads();
        // winners' in-class kept-rank < v <= 32 < 100 by construction
        if (tid < MAXIMG) {
            uint64_t e = outbuf[tid];
            int i = 2047 - (int)(e & 0x7FF);
            int wc = 127 - (int)((e >> 11) & 0x7F);
            float4 b = decode_box(((const float4*)props)[i], ((const float4*)deltas)[i]);
            out[tid*4+0] = b.x;
            out[tid*4+1] = b.y;
            out[tid*4+2] = b.z;
            out[tid*4+3] = b.w;
            out[MAXIMG*4 + tid] = (float)wc;
        }
        if (tid == 0) { g_kcnt = 0; g_bad = 0; }
        return;
    }

    // ============ FALLBACK (correctness net; never runs on bench data) ============
    {
        // recompute boxes + full adjacency from scratch (slow but exact)
        for (int i = tid; i < N_PROP; i += 1024)
            g_boxes[i] = decode_box(((const float4*)props)[i], ((const float4*)deltas)[i]);
        __syncthreads();
        for (int w = tid; w < N_PROP * 64; w += 1024) {
            int rowi = w >> 6, wd = w & 63;
            float4 bi = g_boxes[rowi];
            float ai = fmaxf(bi.z - bi.x, 0.0f) * fmaxf(bi.w - bi.y, 0.0f);
            uint32_t bits = 0u;
            for (int b = 0; b < 32; ++b) {
                int j = wd * 32 + b;
                if (j < N_PROP && j != rowi) {
                    float4 bj = g_boxes[j];
                    float aj = fmaxf(bj.z - bj.x, 0.0f) * fmaxf(bj.w - bj.y, 0.0f);
                    float ix1 = fmaxf(bi.x, bj.x);
                    float iy1 = fmaxf(bi.y, bj.y);
                    float ix2 = fminf(bi.z, bj.z);
                    float iy2 = fminf(bi.w, bj.w);
                    float inter = fmaxf(ix2 - ix1, 0.0f) * fmaxf(iy2 - iy1, 0.0f);
                    float uni = ai + aj - inter;
                    if (inter > 0.7f * uni) bits |= (1u << b);
                }
            }
            g_adj[w] = bits;
        }
        __syncthreads();
        for (int i = tid; i < N_PROP; i += 1024) {
            uint32_t any = 0u;
            for (int w2 = 0; w2 < 64; ++w2) any |= g_adj[i * 64 + w2];
            g_edge[i] = any ? 1 : 0;
        }
        __syncthreads();

        uint32_t* skey = (uint32_t*)(smem + SM_A);
        unsigned char* state = (unsigned char*)(smem + SM_A + 8000);
        uint64_t* cand = cand2;
        for (int c2 = 0; c2 < NCLS; ++c2) {
            for (int i = tid; i < N_PROP; i += 1024) {
                skey[i] = fkey(scores[i * NCLS + c2]);
                state[i] = g_edge[i] ? ST_UNDEC : ST_KEPT;
            }
            if (tid < 3) s_ch[tid] = 0;
            __syncthreads();
            int p = 0;
            for (;;) {
                s_ch[(p+1) % 3] = 0;
                for (int i = tid; i < N_PROP; i += 1024) {
                    if (state[i] != ST_UNDEC) continue;
                    uint32_t ki = skey[i];
                    bool anyKept = false, anyUndec = false;
                    for (int w2 = 0; w2 < 64; ++w2) {
                        uint32_t bits = g_adj[i * 64 + w2];
                        while (bits) {
                            int b = __ffs(bits) - 1; bits &= bits - 1;
                            int j = w2 * 32 + b;
                            uint32_t kj = skey[j];
                            if (kj > ki || (kj == ki && j < i)) {
                                unsigned char stj = state[j];
                                if (stj == ST_KEPT) anyKept = true;
                                else if (stj == ST_UNDEC) anyUndec = true;
                            }
                        }
                    }
                    if (anyKept)        { state[i] = ST_SUPP; s_ch[p] = 1; }
                    else if (!anyUndec) { state[i] = ST_KEPT; s_ch[p] = 1; }
                }
                __syncthreads();
                if (!s_ch[p]) break;
                p = (p + 1) % 3;
            }
            if (tid == 0) sh[5] = 0;
            __syncthreads();
            {
                int local = 0;
                for (int i = tid; i < N_PROP; i += 1024) local += (state[i] == ST_KEPT) ? 1 : 0;
                if (local) atomicAdd(&sh[5], local);
            }
            __syncthreads();
            const int kept = sh[5];
            const int t1 = kept < MAXPC ? kept : MAXPC;
            select_topt(skey, state, ST_KEPT, N_PROP, t1, hist, binF, cand, outbuf, sh);
            for (int r = tid; r < t1; r += 1024) {
                uint64_t e = outbuf[r];
                g_outkey[c2 * MAXPC + r] = (uint32_t)(e >> 32);
                g_outidx[c2 * MAXPC + r] = (int)(0xFFFFFFFFu - (uint32_t)e);
            }
            if (kept < MAXPC) {
                __syncthreads();
                const int t2 = MAXPC - kept;
                select_topt(skey, state, ST_SUPP, N_PROP, t2, hist, binF, cand, outbuf, sh);
                for (int r = tid; r < t2; r += 1024) {
                    uint64_t e = outbuf[r];
                    g_outkey[c2 * MAXPC + kept + r] = FKEY_NEGINF;
                    g_outidx[c2 * MAXPC + kept + r] = (int)(0xFFFFFFFFu - (uint32_t)e);
                }
            }
            __syncthreads();
        }
        uint32_t* gkey = (uint32_t*)(smem + SM_A);
        const uint4* gk4 = (const uint4*)g_outkey;
        uint4* lk4 = (uint4*)gkey;
        for (int q = tid; q < NFLAT/4; q += 1024) lk4[q] = gk4[q];
        __syncthreads();
        select_topt(gkey, nullptr, 0, NFLAT, MAXIMG, hist, binF, cand, outbuf, sh);
        for (int r = tid; r < MAXIMG; r += 1024) {
            uint64_t e = outbuf[r];
            int f = (int)(0xFFFFFFFFu - (uint32_t)e);
            int pi = g_outidx[f];
            float4 b = g_boxes[pi];
            out[r*4+0] = b.x;
            out[r*4+1] = b.y;
            out[r*4+2] = b.z;
            out[r*4+3] = b.w;
            out[MAXIMG*4 + r] = (float)(f / MAXPC);
        }
        if (tid == 0) { g_kcnt = 0; g_bad = 0; }
    }
}

extern "C" void kernel_launch(void* const* d_in, const int* in_sizes, int n_in,
                              void* d_out, int out_size, void* d_ws, size_t ws_size,
                              hipStream_t stream) {
    const float* deltas = (const float*)d_in[0];   // roi_bboxes_txtytwth [2000,4]
    const float* scores = (const float*)d_in[1];   // roi_score [2000,80]
    const float* props  = (const float*)d_in[2];   // rpn_proposals_bboxes [2000,4]
    float* out = (float*)d_out;                    // 1200 box floats + 300 class floats

    class_kernel<<<NCLS, 1024, 0, stream>>>(deltas, props, scores);
    tail_kernel<<<1, 1024, 0, stream>>>(deltas, props, scores, out);
}